// Round 4
// baseline (3191.004 us; speedup 1.0000x reference)
//
#include <hip/hip_runtime.h>

#define EPSV 1e-15f
#define PEPS 1e-5f

typedef float v2f __attribute__((ext_vector_type(2)));

__device__ __forceinline__ float frcp(float x) { return __builtin_amdgcn_rcpf(x); }
__device__ __forceinline__ float fexp2(float x) { return __builtin_amdgcn_exp2f(x); }
__device__ __forceinline__ float flog2(float x) { return __builtin_amdgcn_logf(x); }
__device__ __forceinline__ float projscale(float n2) {
  return n2 > (1.f - PEPS) ? (1.f - PEPS) * frcp(n2) : 1.f;
}

// ---- DPP wave64 sum: v_add_f32_dpp chain, total broadcast via readlane(63) ----
template <int CTRL>
__device__ __forceinline__ float dppadd(float x) {
  int y = __builtin_amdgcn_update_dpp(0, __float_as_int(x), CTRL, 0xF, 0xF, true);
  return x + __int_as_float(y);
}
__device__ __forceinline__ float wave_sum(float x) {
  x = dppadd<0x111>(x);   // row_shr:1
  x = dppadd<0x112>(x);   // row_shr:2
  x = dppadd<0x114>(x);   // row_shr:4
  x = dppadd<0x118>(x);   // row_shr:8
  x = dppadd<0x142>(x);   // row_bcast15
  x = dppadd<0x143>(x);   // row_bcast31
  return __int_as_float(__builtin_amdgcn_readlane(__float_as_int(x), 63));
}

// strided 256-vector access: lane owns cols {l, l+64, l+128, l+192}
__device__ __forceinline__ float4 ld4s(const float* p, int lane) {
  return float4{p[lane], p[lane + 64], p[lane + 128], p[lane + 192]};
}
__device__ __forceinline__ void st4s(float* p, int lane, float4 v) {
  p[lane] = v.x; p[lane + 64] = v.y; p[lane + 128] = v.z; p[lane + 192] = v.w;
}

// ---------------- Kernel A: Ux = mob_mat_mul(u, x) -> out (+EPS folded), vstats -> ws ----------------
__global__ __launch_bounds__(256) void ux_kernel(
    const float* __restrict__ x, const float* __restrict__ u,
    const float* __restrict__ bvec, float* __restrict__ out,
    float4* __restrict__ vstat, int use_vstat)
{
  __shared__ __align__(16) float xsT[256][36];

  const int tid = threadIdx.x;
  const int lane = tid & 63, wv = tid >> 6;
  const long long base = (long long)blockIdx.x * 32;

  #pragma unroll
  for (int k4 = 0; k4 < 8; ++k4) {
    float t0 = x[(base + k4 * 4 + 0) * 256 + tid];
    float t1 = x[(base + k4 * 4 + 1) * 256 + tid];
    float t2 = x[(base + k4 * 4 + 2) * 256 + tid];
    float t3 = x[(base + k4 * 4 + 3) * 256 + tid];
    float4 v; v.x = t0; v.y = t1; v.z = t2; v.w = t3;
    *reinterpret_cast<float4*>(&xsT[tid][k4 * 4]) = v;
  }
  __syncthreads();

  // vb for the vstat dot
  float4 bb = *reinterpret_cast<const float4*>(&bvec[4 * lane]);
  bb.x += EPSV; bb.y += EPSV; bb.z += EPSV; bb.w += EPSV;
  float S_vbrow = wave_sum(bb.x + bb.y + bb.z + bb.w);

  // phase 1: per-row Σx, Σx²
  float s1[8], s2[8];
  #pragma unroll
  for (int r = 0; r < 8; ++r) { s1[r] = 0.f; s2[r] = 0.f; }
  #pragma unroll
  for (int c = 0; c < 4; ++c) {
    const int i = lane + 64 * c;
    float4 xa = *reinterpret_cast<const float4*>(&xsT[i][8 * wv]);
    float4 xb = *reinterpret_cast<const float4*>(&xsT[i][8 * wv + 4]);
    s1[0] += xa.x; s2[0] += xa.x * xa.x;
    s1[1] += xa.y; s2[1] += xa.y * xa.y;
    s1[2] += xa.z; s2[2] += xa.z * xa.z;
    s1[3] += xa.w; s2[3] += xa.w * xa.w;
    s1[4] += xb.x; s2[4] += xb.x * xb.x;
    s1[5] += xb.y; s2[5] += xb.y * xb.y;
    s1[6] += xb.z; s2[6] += xb.z * xb.z;
    s1[7] += xb.w; s2[7] += xb.w * xb.w;
  }
  float rs[8], xnr[8];
  #pragma unroll
  for (int r = 0; r < 8; ++r) {
    float a = wave_sum(s1[r]);
    float b2 = wave_sum(s2[r]);
    float sc = projscale(b2);
    rs[r] = sc;
    xnr[r] = sqrtf(sc * sc * b2 + 2.f * sc * EPSV * a + 256.f * EPSV * EPSV);
  }

  // GEMM
  float4 acc[8];
  #pragma unroll
  for (int r = 0; r < 8; ++r) { acc[r].x = 0.f; acc[r].y = 0.f; acc[r].z = 0.f; acc[r].w = 0.f; }
  #pragma unroll 2
  for (int i = 0; i < 256; ++i) {
    float4 uv = *reinterpret_cast<const float4*>(&u[i * 256 + 4 * lane]);
    float4 xa = *reinterpret_cast<const float4*>(&xsT[i][8 * wv]);
    float4 xb = *reinterpret_cast<const float4*>(&xsT[i][8 * wv + 4]);
    acc[0].x += uv.x * xa.x; acc[0].y += uv.y * xa.x; acc[0].z += uv.z * xa.x; acc[0].w += uv.w * xa.x;
    acc[1].x += uv.x * xa.y; acc[1].y += uv.y * xa.y; acc[1].z += uv.z * xa.y; acc[1].w += uv.w * xa.y;
    acc[2].x += uv.x * xa.z; acc[2].y += uv.y * xa.z; acc[2].z += uv.z * xa.z; acc[2].w += uv.w * xa.z;
    acc[3].x += uv.x * xa.w; acc[3].y += uv.y * xa.w; acc[3].z += uv.z * xa.w; acc[3].w += uv.w * xa.w;
    acc[4].x += uv.x * xb.x; acc[4].y += uv.y * xb.x; acc[4].z += uv.z * xb.x; acc[4].w += uv.w * xb.x;
    acc[5].x += uv.x * xb.y; acc[5].y += uv.y * xb.y; acc[5].z += uv.z * xb.y; acc[5].w += uv.w * xb.y;
    acc[6].x += uv.x * xb.z; acc[6].y += uv.y * xb.z; acc[6].z += uv.z * xb.z; acc[6].w += uv.w * xb.z;
    acc[7].x += uv.x * xb.w; acc[7].y += uv.y * xb.w; acc[7].z += uv.z * xb.w; acc[7].w += uv.w * xb.w;
  }

  // phase 2: ΣMx, ΣMx², Σacc·vb per row; scalar chain; store (+vstats)
  #pragma unroll
  for (int r = 0; r < 8; ++r) {
    float t1 = wave_sum(acc[r].x + acc[r].y + acc[r].z + acc[r].w);
    float t2 = wave_sum(acc[r].x * acc[r].x + acc[r].y * acc[r].y +
                        acc[r].z * acc[r].z + acc[r].w * acc[r].w);
    float t3 = wave_sum(acc[r].x * bb.x + acc[r].y * bb.y + acc[r].z * bb.z + acc[r].w * bb.w);
    float Sm  = rs[r] * t1;
    float Sm2 = rs[r] * rs[r] * t2;
    float mxn = sqrtf(Sm2 + 2.f * EPSV * Sm + 256.f * EPSV * EPSV);
    float xn = xnr[r];
    float at = 0.34657359f * flog2((1.f + xn) * frcp(1.f - xn));
    float arg = mxn * frcp(xn) * at;
    float e2 = fexp2(arg * 2.8853902f);
    float th = 1.f - 2.f * frcp(e2 + 1.f);
    float g = th * frcp(mxn);
    float fs = g * projscale(g * g * Sm2) * rs[r];
    float4 o;
    o.x = fs * acc[r].x + EPSV; o.y = fs * acc[r].y + EPSV;
    o.z = fs * acc[r].z + EPSV; o.w = fs * acc[r].w + EPSV;
    reinterpret_cast<float4*>(out)[(base + 8 * wv + r) * 64 + lane] = o;
    if (use_vstat && lane == 0) {
      float Sv  = fs * t1 + 256.f * EPSV;
      float Sv2 = fs * fs * t2 + 2.f * EPSV * fs * t1 + 256.f * EPSV * EPSV;
      float Svb = fs * t3 + EPSV * S_vbrow;
      vstat[base + 8 * wv + r] = float4{Sv, Sv2, Svb, 0.f};
    }
  }
}

// ---- W-slice load with register pinning (asm-opaque: cannot be re-loaded in-loop) ----
template <int NR>
__device__ __forceinline__ void load_w(const float* __restrict__ w, int rb, int lane, v2f* wr) {
  #pragma unroll
  for (int r = 0; r < NR; ++r) {
    const float* p = &w[(rb + r) * 256 + lane];
    float a = p[0], b = p[64], c = p[128], d = p[192];
    asm volatile("" : "+v"(a), "+v"(b), "+v"(c), "+v"(d));
    wr[2 * r]     = v2f{a, b};
    wr[2 * r + 1] = v2f{c, d};
  }
}

// ---- P,Q matvec over NR rows: P=W@mx, Q=W@v (v2f pairs -> v_pk_fma_f32) ----
template <int NR>
__device__ __forceinline__ void mv_pq(const v2f* wr, const float* mxp, const float* vp,
                                      float4& P, float4& Q) {
  v2f pl{0.f, 0.f}, ph{0.f, 0.f}, ql{0.f, 0.f}, qh{0.f, 0.f};
  #pragma unroll
  for (int i = 0; i < NR / 4; ++i) {
    float4 h4 = *reinterpret_cast<const float4*>(mxp + 4 * i);
    float4 u4 = *reinterpret_cast<const float4*>(vp + 4 * i);
    pl += wr[8 * i + 0] * h4.x; ph += wr[8 * i + 1] * h4.x;
    pl += wr[8 * i + 2] * h4.y; ph += wr[8 * i + 3] * h4.y;
    pl += wr[8 * i + 4] * h4.z; ph += wr[8 * i + 5] * h4.z;
    pl += wr[8 * i + 6] * h4.w; ph += wr[8 * i + 7] * h4.w;
    ql += wr[8 * i + 0] * u4.x; qh += wr[8 * i + 1] * u4.x;
    ql += wr[8 * i + 2] * u4.y; qh += wr[8 * i + 3] * u4.y;
    ql += wr[8 * i + 4] * u4.z; qh += wr[8 * i + 5] * u4.z;
    ql += wr[8 * i + 6] * u4.w; qh += wr[8 * i + 7] * u4.w;
  }
  P = float4{pl.x, pl.y, ph.x, ph.y};
  Q = float4{ql.x, ql.y, qh.x, qh.y};
}

#define ATOMIC_PQ(b)                                             \
  atomicAdd(&psum[b][lane],       P.x);                          \
  atomicAdd(&psum[b][lane + 64],  P.y);                          \
  atomicAdd(&psum[b][lane + 128], P.z);                          \
  atomicAdd(&psum[b][lane + 192], P.w);                          \
  atomicAdd(&qsum[b][lane],       Q.x);                          \
  atomicAdd(&qsum[b][lane + 64],  Q.y);                          \
  atomicAdd(&qsum[b][lane + 128], Q.z);                          \
  atomicAdd(&qsum[b][lane + 192], Q.w);

// ---------------- Kernel B: recurrence. 8 waves; wave0 = 4 W-rows + serial chain ----------------
__global__ __launch_bounds__(512, 2) void rnn_kernel(
    const float* __restrict__ w, const float* __restrict__ bvec,
    float* __restrict__ out, const float4* __restrict__ vstat, int S, int use_vstat)
{
  __shared__ __align__(16) float mx_lds[256];
  __shared__ __align__(16) float v_lds[2][256];
  __shared__ __align__(16) float psum[2][256];
  __shared__ __align__(16) float qsum[2][256];

  const int tid = threadIdx.x;
  const int lane = tid & 63;
  const int wv = tid >> 6;                     // 0..7

  const long long rowbase = (long long)blockIdx.x * S * 256;
  const long long vsbase = (long long)blockIdx.x * S;
  const float4 zero4{0.f, 0.f, 0.f, 0.f};

  if (wv == 0) {
    v2f wr0[8];
    load_w<4>(w, 0, lane, wr0);

    float4 vb4{bvec[lane] + EPSV, bvec[lane + 64] + EPSV,
               bvec[lane + 128] + EPSV, bvec[lane + 192] + EPSV};
    float S_vb  = wave_sum(vb4.x + vb4.y + vb4.z + vb4.w);
    float S_vb2 = wave_sum(vb4.x * vb4.x + vb4.y * vb4.y + vb4.z * vb4.z + vb4.w * vb4.w);

    // prologue zeroing + stage vb for the Wvb init matvec
    reinterpret_cast<float4*>(mx_lds)[lane]   = zero4;
    reinterpret_cast<float4*>(psum[0])[lane]  = zero4;
    reinterpret_cast<float4*>(psum[1])[lane]  = zero4;
    reinterpret_cast<float4*>(qsum[0])[lane]  = zero4;
    reinterpret_cast<float4*>(qsum[1])[lane]  = zero4;
    st4s(v_lds[0], lane, vb4);
    __syncthreads();                            // (1)

    { float4 P, Q; mv_pq<4>(wr0, &mx_lds[0], &v_lds[0][0], P, Q); ATOMIC_PQ(0) }
    __syncthreads();                            // (2)

    float4 Wvb4 = ld4s(qsum[0], lane);
    reinterpret_cast<float4*>(qsum[0])[lane] = zero4;
    float4 vA = ld4s(out + rowbase, lane);
    float4 vB = ld4s(out + rowbase + 256, lane);
    float4 sA{0.f,0.f,0.f,0.f}, sB{0.f,0.f,0.f,0.f};
    if (use_vstat) { sA = vstat[vsbase]; sB = vstat[vsbase + 1]; }
    st4s(v_lds[0], lane, vA);
    __syncthreads();                            // (3)

    float4 m4 = zero4;                          // Mx[0] (h0 = 0)
    float S_h = 0.f, S_h2 = 0.f;

    for (int t = 0; t < S; ++t) {
      const int b = t & 1;
      float4 v4 = vA;                           // EPS already folded by ux_kernel

      // 4 recurrence-dependent dots (DPP)
      float S_Mx  = wave_sum(m4.x + m4.y + m4.z + m4.w);
      float S_Mx2 = wave_sum(m4.x * m4.x + m4.y * m4.y + m4.z * m4.z + m4.w * m4.w);
      float S_Mxv = wave_sum(m4.x * v4.x + m4.y * v4.y + m4.z * v4.z + m4.w * v4.w);
      float S_Mxb = wave_sum(m4.x * vb4.x + m4.y * vb4.y + m4.z * vb4.z + m4.w * vb4.w);
      float S_v, S_v2, S_vvb;
      if (use_vstat) { S_v = sA.x; S_v2 = sA.y; S_vvb = sA.z; }
      else {
        S_v   = wave_sum(v4.x + v4.y + v4.z + v4.w);
        S_v2  = wave_sum(v4.x * v4.x + v4.y * v4.y + v4.z * v4.z + v4.w * v4.w);
        S_vvb = wave_sum(v4.x * vb4.x + v4.y * vb4.y + v4.z * vb4.z + v4.w * vb4.w);
      }

      // scalar chain (wave-uniform)
      float s_hp = projscale(S_h2);
      float xn = sqrtf(s_hp * s_hp * S_h2 + 2.f * s_hp * EPSV * S_h + 256.f * EPSV * EPSV);
      float mxn = sqrtf(S_Mx2 + 2.f * EPSV * S_Mx + 256.f * EPSV * EPSV);
      float at = 0.34657359f * flog2((1.f + xn) * frcp(1.f - xn));
      float arg = mxn * frcp(xn) * at;
      float e2 = fexp2(arg * 2.8853902f);
      float th = 1.f - 2.f * frcp(e2 + 1.f);
      float g = th * frcp(mxn);
      float beta = g * projscale(g * g * S_Mx2);

      float nuv = 2.f * beta * S_Mxv;
      float nu  = beta * beta * S_Mx2;
      float nv  = S_v2;
      float rden = frcp(1.f + nuv + nv * nu);
      float cA = (1.f + nuv + nv) * rden;
      float cB = (1.f - nu) * rden;
      float cAb = cA * beta;
      float S_r1  = cAb * S_Mx + cB * S_v;
      float S_r12 = cAb * cAb * S_Mx2 + 2.f * cAb * cB * S_Mxv + cB * cB * S_v2;
      float S_r1b = cAb * S_Mxb + cB * S_vvb;
      float s1p = projscale(S_r12);
      float S_U = s1p * S_r1, S_U2 = s1p * s1p * S_r12, S_Ub = s1p * S_r1b;

      float nuv2 = 2.f * S_Ub;
      float rden2 = frcp(1.f + nuv2 + S_vb2 * S_U2);
      float dA = (1.f + nuv2 + S_vb2) * rden2;
      float dB = (1.f - S_U2) * rden2;
      float S_hn  = dA * S_U + dB * S_vb;
      float S_hn2 = dA * dA * S_U2 + 2.f * dA * dB * S_Ub + dB * dB * S_vb2;
      float s2p = projscale(S_hn2);

      float km = s2p * dA * s1p * cAb;
      float kv = s2p * dA * s1p * cB;
      float kb = s2p * dB;

      float4 hn{km * m4.x + kv * v4.x + kb * vb4.x,
                km * m4.y + kv * v4.y + kb * vb4.y,
                km * m4.z + kv * v4.z + kb * vb4.z,
                km * m4.w + kv * v4.w + kb * vb4.w};
      st4s(out + rowbase + (long long)t * 256, lane, hn);

      S_h  = s2p * S_hn;
      S_h2 = s2p * s2p * S_hn2;
      float snextp = projscale(S_h2);

      // stage v[t+1], prefetch v[t+2]
      if (t + 1 < S) st4s(v_lds[(t + 1) & 1], lane, vB);
      float4 vC = vB, sC = sB;
      if (t + 2 < S) {
        vC = ld4s(out + rowbase + (long long)(t + 2) * 256, lane);
        if (use_vstat) sC = vstat[vsbase + t + 2];
      }

      // own 4-row matvec
      { float4 P, Q; mv_pq<4>(wr0, &mx_lds[0], &v_lds[b][0], P, Q); ATOMIC_PQ(b) }
      __syncthreads();                          // B: all partials in

      // epoch B: combine -> Mx[t+1], write, zero buffers
      float4 Pc = ld4s(psum[b], lane);
      float4 Qc = ld4s(qsum[b], lane);
      m4.x = snextp * (km * Pc.x + kv * Qc.x + kb * Wvb4.x);
      m4.y = snextp * (km * Pc.y + kv * Qc.y + kb * Wvb4.y);
      m4.z = snextp * (km * Pc.z + kv * Qc.z + kb * Wvb4.z);
      m4.w = snextp * (km * Pc.w + kv * Qc.w + kb * Wvb4.w);
      st4s(mx_lds, lane, m4);
      reinterpret_cast<float4*>(psum[b])[lane] = zero4;
      reinterpret_cast<float4*>(qsum[b])[lane] = zero4;
      __syncthreads();                          // A

      vA = vB; vB = vC; sA = sB; sB = sC;
    }
  } else {
    const int rb = 4 + (wv - 1) * 36;
    v2f wrk[72];
    load_w<36>(w, rb, lane, wrk);
    __syncthreads();                            // (1)
    { float4 P, Q; mv_pq<36>(wrk, &mx_lds[rb], &v_lds[0][rb], P, Q); ATOMIC_PQ(0) }
    __syncthreads();                            // (2)
    __syncthreads();                            // (3)

    for (int t = 0; t < S; ++t) {
      const int b = t & 1;
      float4 P, Q;
      mv_pq<36>(wrk, &mx_lds[rb], &v_lds[b][rb], P, Q);
      ATOMIC_PQ(b)
      __syncthreads();                          // B
      __syncthreads();                          // A
    }
  }
}

extern "C" void kernel_launch(void* const* d_in, const int* in_sizes, int n_in,
                              void* d_out, int out_size, void* d_ws, size_t ws_size,
                              hipStream_t stream) {
  const float* x = (const float*)d_in[0];   // [B,S,I]
  const float* w = (const float*)d_in[1];   // [H,H]
  const float* u = (const float*)d_in[2];   // [I,H]
  const float* b = (const float*)d_in[3];   // [H]
  float* out = (float*)d_out;               // [B,S,H]

  const int nrows = in_sizes[0] / 256;      // B*S
  const int S = 512;
  const int B = nrows / S;

  const int use_vstat = (ws_size >= (size_t)nrows * 16) ? 1 : 0;
  float4* vstat = (float4*)d_ws;

  ux_kernel<<<nrows / 32, 256, 0, stream>>>(x, u, b, out, vstat, use_vstat);
  rnn_kernel<<<B, 512, 0, stream>>>(w, b, out, vstat, S, use_vstat);
}

// Round 5
// 906.237 us; speedup vs baseline: 3.5212x; 3.5212x over previous
//
#include <hip/hip_runtime.h>

#define EPSV 1e-15f
#define PEPS 1e-5f

typedef float v2f __attribute__((ext_vector_type(2)));

__device__ __forceinline__ float frcp(float x) { return __builtin_amdgcn_rcpf(x); }
__device__ __forceinline__ float fexp2(float x) { return __builtin_amdgcn_exp2f(x); }
__device__ __forceinline__ float flog2(float x) { return __builtin_amdgcn_logf(x); }
__device__ __forceinline__ float projscale(float n2) {
  return n2 > (1.f - PEPS) ? (1.f - PEPS) * frcp(n2) : 1.f;
}

// ---- DPP wave64 sum ----
template <int CTRL>
__device__ __forceinline__ float dppadd(float x) {
  int y = __builtin_amdgcn_update_dpp(0, __float_as_int(x), CTRL, 0xF, 0xF, true);
  return x + __int_as_float(y);
}
__device__ __forceinline__ float wave_sum(float x) {
  x = dppadd<0x111>(x);
  x = dppadd<0x112>(x);
  x = dppadd<0x114>(x);
  x = dppadd<0x118>(x);
  x = dppadd<0x142>(x);   // row_bcast15
  x = dppadd<0x143>(x);   // row_bcast31
  return __int_as_float(__builtin_amdgcn_readlane(__float_as_int(x), 63));
}

// ---------------- Kernel A: Ux = mob_mat_mul(u, x) -> out (+EPS folded), vstats -> ws ----------------
__global__ __launch_bounds__(256) void ux_kernel(
    const float* __restrict__ x, const float* __restrict__ u,
    const float* __restrict__ bvec, float* __restrict__ out,
    float4* __restrict__ vstat, int use_vstat)
{
  __shared__ __align__(16) float xsT[256][36];

  const int tid = threadIdx.x;
  const int lane = tid & 63, wv = tid >> 6;
  const long long base = (long long)blockIdx.x * 32;

  #pragma unroll
  for (int k4 = 0; k4 < 8; ++k4) {
    float t0 = x[(base + k4 * 4 + 0) * 256 + tid];
    float t1 = x[(base + k4 * 4 + 1) * 256 + tid];
    float t2 = x[(base + k4 * 4 + 2) * 256 + tid];
    float t3 = x[(base + k4 * 4 + 3) * 256 + tid];
    float4 v; v.x = t0; v.y = t1; v.z = t2; v.w = t3;
    *reinterpret_cast<float4*>(&xsT[tid][k4 * 4]) = v;
  }
  __syncthreads();

  float4 bb = *reinterpret_cast<const float4*>(&bvec[4 * lane]);
  bb.x += EPSV; bb.y += EPSV; bb.z += EPSV; bb.w += EPSV;
  float S_vbrow = wave_sum(bb.x + bb.y + bb.z + bb.w);

  float s1[8], s2[8];
  #pragma unroll
  for (int r = 0; r < 8; ++r) { s1[r] = 0.f; s2[r] = 0.f; }
  #pragma unroll
  for (int c = 0; c < 4; ++c) {
    const int i = lane + 64 * c;
    float4 xa = *reinterpret_cast<const float4*>(&xsT[i][8 * wv]);
    float4 xb = *reinterpret_cast<const float4*>(&xsT[i][8 * wv + 4]);
    s1[0] += xa.x; s2[0] += xa.x * xa.x;
    s1[1] += xa.y; s2[1] += xa.y * xa.y;
    s1[2] += xa.z; s2[2] += xa.z * xa.z;
    s1[3] += xa.w; s2[3] += xa.w * xa.w;
    s1[4] += xb.x; s2[4] += xb.x * xb.x;
    s1[5] += xb.y; s2[5] += xb.y * xb.y;
    s1[6] += xb.z; s2[6] += xb.z * xb.z;
    s1[7] += xb.w; s2[7] += xb.w * xb.w;
  }
  float rs[8], xnr[8];
  #pragma unroll
  for (int r = 0; r < 8; ++r) {
    float a = wave_sum(s1[r]);
    float b2 = wave_sum(s2[r]);
    float sc = projscale(b2);
    rs[r] = sc;
    xnr[r] = sqrtf(sc * sc * b2 + 2.f * sc * EPSV * a + 256.f * EPSV * EPSV);
  }

  float4 acc[8];
  #pragma unroll
  for (int r = 0; r < 8; ++r) { acc[r].x = 0.f; acc[r].y = 0.f; acc[r].z = 0.f; acc[r].w = 0.f; }
  #pragma unroll 2
  for (int i = 0; i < 256; ++i) {
    float4 uv = *reinterpret_cast<const float4*>(&u[i * 256 + 4 * lane]);
    float4 xa = *reinterpret_cast<const float4*>(&xsT[i][8 * wv]);
    float4 xb = *reinterpret_cast<const float4*>(&xsT[i][8 * wv + 4]);
    acc[0].x += uv.x * xa.x; acc[0].y += uv.y * xa.x; acc[0].z += uv.z * xa.x; acc[0].w += uv.w * xa.x;
    acc[1].x += uv.x * xa.y; acc[1].y += uv.y * xa.y; acc[1].z += uv.z * xa.y; acc[1].w += uv.w * xa.y;
    acc[2].x += uv.x * xa.z; acc[2].y += uv.y * xa.z; acc[2].z += uv.z * xa.z; acc[2].w += uv.w * xa.z;
    acc[3].x += uv.x * xa.w; acc[3].y += uv.y * xa.w; acc[3].z += uv.z * xa.w; acc[3].w += uv.w * xa.w;
    acc[4].x += uv.x * xb.x; acc[4].y += uv.y * xb.x; acc[4].z += uv.z * xb.x; acc[4].w += uv.w * xb.x;
    acc[5].x += uv.x * xb.y; acc[5].y += uv.y * xb.y; acc[5].z += uv.z * xb.y; acc[5].w += uv.w * xb.y;
    acc[6].x += uv.x * xb.z; acc[6].y += uv.y * xb.z; acc[6].z += uv.z * xb.z; acc[6].w += uv.w * xb.z;
    acc[7].x += uv.x * xb.w; acc[7].y += uv.y * xb.w; acc[7].z += uv.z * xb.w; acc[7].w += uv.w * xb.w;
  }

  #pragma unroll
  for (int r = 0; r < 8; ++r) {
    float t1 = wave_sum(acc[r].x + acc[r].y + acc[r].z + acc[r].w);
    float t2 = wave_sum(acc[r].x * acc[r].x + acc[r].y * acc[r].y +
                        acc[r].z * acc[r].z + acc[r].w * acc[r].w);
    float t3 = wave_sum(acc[r].x * bb.x + acc[r].y * bb.y + acc[r].z * bb.z + acc[r].w * bb.w);
    float Sm  = rs[r] * t1;
    float Sm2 = rs[r] * rs[r] * t2;
    float mxn = sqrtf(Sm2 + 2.f * EPSV * Sm + 256.f * EPSV * EPSV);
    float xn = xnr[r];
    float at = 0.34657359f * flog2((1.f + xn) * frcp(1.f - xn));
    float arg = mxn * frcp(xn) * at;
    float e2 = fexp2(arg * 2.8853902f);
    float th = 1.f - 2.f * frcp(e2 + 1.f);
    float g = th * frcp(mxn);
    float fs = g * projscale(g * g * Sm2) * rs[r];
    float4 o;
    o.x = fs * acc[r].x + EPSV; o.y = fs * acc[r].y + EPSV;
    o.z = fs * acc[r].z + EPSV; o.w = fs * acc[r].w + EPSV;
    reinterpret_cast<float4*>(out)[(base + 8 * wv + r) * 64 + lane] = o;
    if (use_vstat && lane == 0) {
      float Sv  = fs * t1 + 256.f * EPSV;
      float Sv2 = fs * fs * t2 + 2.f * EPSV * fs * t1 + 256.f * EPSV * EPSV;
      float Svb = fs * t3 + EPSV * S_vbrow;
      vstat[base + 8 * wv + r] = float4{Sv, Sv2, Svb, 0.f};
    }
  }
}

// ---- W-slice load, coalesced b128, pinned opaque (no remat possible) ----
template <int NR>
__device__ __forceinline__ void load_w(const float* __restrict__ w, int rb, int lane, v2f* wr) {
  #pragma unroll
  for (int r = 0; r < NR; ++r) {
    float4 t = *reinterpret_cast<const float4*>(&w[(rb + r) * 256 + 4 * lane]);
    asm volatile("" : "+v"(t.x), "+v"(t.y), "+v"(t.z), "+v"(t.w));
    wr[2 * r]     = v2f{t.x, t.y};
    wr[2 * r + 1] = v2f{t.z, t.w};
  }
}

// ---- P,Q matvec over NR rows (packed v_pk_fma_f32); cols 4*lane..+3 ----
template <int NR>
__device__ __forceinline__ void mv_pq(const v2f* wr, const float* mxp, const float* vp,
                                      float4& P, float4& Q) {
  v2f pl{0.f, 0.f}, ph{0.f, 0.f}, ql{0.f, 0.f}, qh{0.f, 0.f};
  #pragma unroll
  for (int i = 0; i < NR / 4; ++i) {
    float4 h4 = *reinterpret_cast<const float4*>(mxp + 4 * i);   // wave-uniform broadcast
    float4 u4 = *reinterpret_cast<const float4*>(vp + 4 * i);
    pl += wr[8 * i + 0] * h4.x; ph += wr[8 * i + 1] * h4.x;
    pl += wr[8 * i + 2] * h4.y; ph += wr[8 * i + 3] * h4.y;
    pl += wr[8 * i + 4] * h4.z; ph += wr[8 * i + 5] * h4.z;
    pl += wr[8 * i + 6] * h4.w; ph += wr[8 * i + 7] * h4.w;
    ql += wr[8 * i + 0] * u4.x; qh += wr[8 * i + 1] * u4.x;
    ql += wr[8 * i + 2] * u4.y; qh += wr[8 * i + 3] * u4.y;
    ql += wr[8 * i + 4] * u4.z; qh += wr[8 * i + 5] * u4.z;
    ql += wr[8 * i + 6] * u4.w; qh += wr[8 * i + 7] * u4.w;
  }
  P = float4{pl.x, pl.y, ph.x, ph.y};
  Q = float4{ql.x, ql.y, qh.x, qh.y};
}

// ---------------- Kernel B: recurrence. 8 waves, W fully register-resident ----------------
// wave0: W rows 0-3 + all serial work. waves 1-7: 36 W rows each (144 VGPRs).
__global__ __launch_bounds__(512, 1) void rnn_kernel(
    const float* __restrict__ w, const float* __restrict__ bvec,
    float* __restrict__ out, const float4* __restrict__ vstat, int S, int use_vstat)
{
  __shared__ __align__(16) float mx_lds[256];
  __shared__ __align__(16) float v_lds[2][256];
  __shared__ __align__(16) float pP[8][256];
  __shared__ __align__(16) float pQ[8][256];

  const int tid = threadIdx.x;
  const int lane = tid & 63;
  const int wv = tid >> 6;                     // 0..7

  const long long rb4 = (long long)blockIdx.x * S * 64;   // float4 units
  const long long vsbase = (long long)blockIdx.x * S;
  const float4* outv = reinterpret_cast<const float4*>(out);
  float4* outw = reinterpret_cast<float4*>(out);
  const float4 zero4{0.f, 0.f, 0.f, 0.f};

  if (wv == 0) {
    v2f wr0[8];
    load_w<4>(w, 0, lane, wr0);

    float4 vb4 = *reinterpret_cast<const float4*>(&bvec[4 * lane]);
    vb4.x += EPSV; vb4.y += EPSV; vb4.z += EPSV; vb4.w += EPSV;
    float S_vb  = wave_sum(vb4.x + vb4.y + vb4.z + vb4.w);
    float S_vb2 = wave_sum(vb4.x * vb4.x + vb4.y * vb4.y + vb4.z * vb4.z + vb4.w * vb4.w);

    reinterpret_cast<float4*>(mx_lds)[lane] = zero4;
    reinterpret_cast<float4*>(v_lds[0])[lane] = vb4;      // stage vb for Wvb init matvec
    __syncthreads();  // (1)

    {
      float4 P, Q; mv_pq<4>(wr0, &mx_lds[0], &v_lds[0][0], P, Q);
      *reinterpret_cast<float4*>(&pP[0][4 * lane]) = P;
      *reinterpret_cast<float4*>(&pQ[0][4 * lane]) = Q;
    }
    __syncthreads();  // (2)

    float4 Wvb4 = zero4;
    #pragma unroll
    for (int k = 0; k < 8; ++k) {
      float4 qq = *reinterpret_cast<const float4*>(&pQ[k][4 * lane]);
      Wvb4.x += qq.x; Wvb4.y += qq.y; Wvb4.z += qq.z; Wvb4.w += qq.w;
    }
    float4 vA = outv[rb4 + lane];        // v[0] (EPS folded by ux_kernel)
    float4 vB = outv[rb4 + 64 + lane];   // v[1]
    float4 sA = zero4, sB = zero4;
    if (use_vstat) { sA = vstat[vsbase]; sB = vstat[vsbase + 1]; }
    reinterpret_cast<float4*>(v_lds[0])[lane] = vA;       // real v[0]
    __syncthreads();  // (3)

    float4 m4 = zero4;                   // Mx[0] (h0 = 0)
    float S_h = 0.f, S_h2 = 0.f;

    for (int t = 0; t < S; ++t) {
      const int b = t & 1;
      float4 v4 = vA;

      // recurrence-dependent dots (DPP)
      float S_Mx  = wave_sum(m4.x + m4.y + m4.z + m4.w);
      float S_Mx2 = wave_sum(m4.x * m4.x + m4.y * m4.y + m4.z * m4.z + m4.w * m4.w);
      float S_Mxv = wave_sum(m4.x * v4.x + m4.y * v4.y + m4.z * v4.z + m4.w * v4.w);
      float S_Mxb = wave_sum(m4.x * vb4.x + m4.y * vb4.y + m4.z * vb4.z + m4.w * vb4.w);
      float S_v, S_v2, S_vvb;
      if (use_vstat) { S_v = sA.x; S_v2 = sA.y; S_vvb = sA.z; }
      else {
        S_v   = wave_sum(v4.x + v4.y + v4.z + v4.w);
        S_v2  = wave_sum(v4.x * v4.x + v4.y * v4.y + v4.z * v4.z + v4.w * v4.w);
        S_vvb = wave_sum(v4.x * vb4.x + v4.y * vb4.y + v4.z * vb4.z + v4.w * vb4.w);
      }

      // scalar chain (wave-uniform)
      float s_hp = projscale(S_h2);
      float xn = sqrtf(s_hp * s_hp * S_h2 + 2.f * s_hp * EPSV * S_h + 256.f * EPSV * EPSV);
      float mxn = sqrtf(S_Mx2 + 2.f * EPSV * S_Mx + 256.f * EPSV * EPSV);
      float at = 0.34657359f * flog2((1.f + xn) * frcp(1.f - xn));
      float arg = mxn * frcp(xn) * at;
      float e2 = fexp2(arg * 2.8853902f);
      float th = 1.f - 2.f * frcp(e2 + 1.f);
      float g = th * frcp(mxn);
      float beta = g * projscale(g * g * S_Mx2);

      float nuv = 2.f * beta * S_Mxv;
      float nu  = beta * beta * S_Mx2;
      float nv  = S_v2;
      float rden = frcp(1.f + nuv + nv * nu);
      float cA = (1.f + nuv + nv) * rden;
      float cB = (1.f - nu) * rden;
      float cAb = cA * beta;
      float S_r1  = cAb * S_Mx + cB * S_v;
      float S_r12 = cAb * cAb * S_Mx2 + 2.f * cAb * cB * S_Mxv + cB * cB * S_v2;
      float S_r1b = cAb * S_Mxb + cB * S_vvb;
      float s1p = projscale(S_r12);
      float S_U = s1p * S_r1, S_U2 = s1p * s1p * S_r12, S_Ub = s1p * S_r1b;

      float nuv2 = 2.f * S_Ub;
      float rden2 = frcp(1.f + nuv2 + S_vb2 * S_U2);
      float dA = (1.f + nuv2 + S_vb2) * rden2;
      float dB = (1.f - S_U2) * rden2;
      float S_hn  = dA * S_U + dB * S_vb;
      float S_hn2 = dA * dA * S_U2 + 2.f * dA * dB * S_Ub + dB * dB * S_vb2;
      float s2p = projscale(S_hn2);

      float km = s2p * dA * s1p * cAb;
      float kv = s2p * dA * s1p * cB;
      float kb = s2p * dB;

      float4 hn{km * m4.x + kv * v4.x + kb * vb4.x,
                km * m4.y + kv * v4.y + kb * vb4.y,
                km * m4.z + kv * v4.z + kb * vb4.z,
                km * m4.w + kv * v4.w + kb * vb4.w};
      outw[rb4 + (long long)t * 64 + lane] = hn;

      S_h  = s2p * S_hn;
      S_h2 = s2p * s2p * S_hn2;
      float snextp = projscale(S_h2);

      // stage v[t+1], prefetch v[t+2]
      if (t + 1 < S) reinterpret_cast<float4*>(v_lds[(t + 1) & 1])[lane] = vB;
      float4 vC = vB, sC = sB;
      if (t + 2 < S) {
        vC = outv[rb4 + (long long)(t + 2) * 64 + lane];
        if (use_vstat) sC = vstat[vsbase + t + 2];
      }

      // own 4-row matvec
      {
        float4 P, Q; mv_pq<4>(wr0, &mx_lds[0], &v_lds[b][0], P, Q);
        *reinterpret_cast<float4*>(&pP[0][4 * lane]) = P;
        *reinterpret_cast<float4*>(&pQ[0][4 * lane]) = Q;
      }
      __syncthreads();                          // B: all partials in

      // combine -> Mx[t+1]
      float4 Pc = zero4, Qc = zero4;
      #pragma unroll
      for (int k = 0; k < 8; ++k) {
        float4 pp = *reinterpret_cast<const float4*>(&pP[k][4 * lane]);
        float4 qq = *reinterpret_cast<const float4*>(&pQ[k][4 * lane]);
        Pc.x += pp.x; Pc.y += pp.y; Pc.z += pp.z; Pc.w += pp.w;
        Qc.x += qq.x; Qc.y += qq.y; Qc.z += qq.z; Qc.w += qq.w;
      }
      m4.x = snextp * (km * Pc.x + kv * Qc.x + kb * Wvb4.x);
      m4.y = snextp * (km * Pc.y + kv * Qc.y + kb * Wvb4.y);
      m4.z = snextp * (km * Pc.z + kv * Qc.z + kb * Wvb4.z);
      m4.w = snextp * (km * Pc.w + kv * Qc.w + kb * Wvb4.w);
      reinterpret_cast<float4*>(mx_lds)[lane] = m4;
      __syncthreads();                          // A

      vA = vB; vB = vC; sA = sB; sB = sC;
    }
  } else {
    const int rb = 4 + (wv - 1) * 36;
    v2f wrk[72];
    load_w<36>(w, rb, lane, wrk);
    __syncthreads();                            // (1)
    {
      float4 P, Q; mv_pq<36>(wrk, &mx_lds[rb], &v_lds[0][rb], P, Q);
      *reinterpret_cast<float4*>(&pP[wv][4 * lane]) = P;
      *reinterpret_cast<float4*>(&pQ[wv][4 * lane]) = Q;
    }
    __syncthreads();                            // (2)
    __syncthreads();                            // (3)

    for (int t = 0; t < S; ++t) {
      const int b = t & 1;
      float4 P, Q;
      mv_pq<36>(wrk, &mx_lds[rb], &v_lds[b][rb], P, Q);
      *reinterpret_cast<float4*>(&pP[wv][4 * lane]) = P;
      *reinterpret_cast<float4*>(&pQ[wv][4 * lane]) = Q;
      __syncthreads();                          // B
      __syncthreads();                          // A
    }
  }
}

extern "C" void kernel_launch(void* const* d_in, const int* in_sizes, int n_in,
                              void* d_out, int out_size, void* d_ws, size_t ws_size,
                              hipStream_t stream) {
  const float* x = (const float*)d_in[0];   // [B,S,I]
  const float* w = (const float*)d_in[1];   // [H,H]
  const float* u = (const float*)d_in[2];   // [I,H]
  const float* b = (const float*)d_in[3];   // [H]
  float* out = (float*)d_out;               // [B,S,H]

  const int nrows = in_sizes[0] / 256;      // B*S
  const int S = 512;
  const int B = nrows / S;

  const int use_vstat = (ws_size >= (size_t)nrows * 16) ? 1 : 0;
  float4* vstat = (float4*)d_ws;

  ux_kernel<<<nrows / 32, 256, 0, stream>>>(x, u, b, out, vstat, use_vstat);
  rnn_kernel<<<B, 512, 0, stream>>>(w, b, out, vstat, S, use_vstat);
}